// Round 3
// baseline (237.582 us; speedup 1.0000x reference)
//
#include <hip/hip_runtime.h>
#include <math.h>
#include <stdint.h>

#define BN 4
#define TN 4096
#define EN 1024
#define HN 64
#define BT (BN*TN)

typedef __attribute__((ext_vector_type(8))) short   short8;   // 8 bf16 (4 VGPR) MFMA frag
typedef __attribute__((ext_vector_type(4))) float   f32x4;    // MFMA acc
typedef __attribute__((ext_vector_type(4))) unsigned short us4;
typedef __attribute__((ext_vector_type(8))) unsigned short us8;

// fp32 -> bf16 RNE
__device__ __forceinline__ unsigned short f2b(float f) {
    union { float f; uint32_t u; } v; v.f = f;
    uint32_t u = v.u;
    return (unsigned short)((u + 0x7FFFu + ((u >> 16) & 1u)) >> 16);
}

__device__ __forceinline__ float fexp2(float x) {
#if __has_builtin(__builtin_amdgcn_exp2f)
    return __builtin_amdgcn_exp2f(x);
#else
    return exp2f(x);
#endif
}

// ---------------------------------------------------------------------------
// W -> bf16. Rows 0-63: Wq scaled by log2(e)/32 (softmax runs in exp2 domain).
// Rows 64-127: Wk. Rows 128-191: Wv. Grid 192 x 256 (one row/block).
// ---------------------------------------------------------------------------
__global__ __launch_bounds__(256)
void wconv(const float* __restrict__ Wq, const float* __restrict__ Wk,
           const float* __restrict__ Wv, unsigned short* __restrict__ W16) {
    const int row = blockIdx.x;
    const int t = threadIdx.x;
    const float* src;
    float sc = 1.0f;
    if (row < 64)       { src = Wq + (size_t)row * EN; sc = 0.045084220f; }
    else if (row < 128) { src = Wk + (size_t)(row - 64) * EN; }
    else                { src = Wv + (size_t)(row - 128) * EN; }
    float4 v = *(const float4*)(src + t * 4);
    us4 p;
    p[0] = f2b(v.x * sc); p[1] = f2b(v.y * sc);
    p[2] = f2b(v.z * sc); p[3] = f2b(v.w * sc);
    *(us4*)&W16[(size_t)row * EN + t * 4] = p;
}

// ---------------------------------------------------------------------------
// QKV projection GEMM: C[16384][192] = emb[16384][1024] * W16^T, bf16 MFMA.
// Block: 64 rows x 192 cols, 4 waves in 2x2 (wm: 32 rows, wn: 96 cols).
// Q,K written [wsel][r][d]; V written transposed [b][d][t] for attention.
// ---------------------------------------------------------------------------
__global__ __launch_bounds__(256)
void qkv_gemm(const float* __restrict__ emb, const unsigned short* __restrict__ W16,
              unsigned short* __restrict__ QK, unsigned short* __restrict__ VT) {
    __shared__ __align__(16) unsigned short A_lds[64][40];    // pad 40: odd 16B mult
    __shared__ __align__(16) unsigned short B_lds[192][40];

    const int tid = threadIdx.x;
    const int wid = tid >> 6;
    const int lane = tid & 63;
    const int c = lane & 15, g = lane >> 4;
    const int wm = wid & 1, wn = wid >> 1;
    const int r0 = blockIdx.x * 64;

    const f32x4 fzero = {0.f, 0.f, 0.f, 0.f};
    f32x4 acc[2][6];
    #pragma unroll
    for (int i = 0; i < 2; ++i)
        #pragma unroll
        for (int j = 0; j < 6; ++j) acc[i][j] = fzero;

    for (int k0 = 0; k0 < EN; k0 += 32) {
        // stage A: 64x32 fp32 -> bf16
        #pragma unroll
        for (int s = 0; s < 2; ++s) {
            int f = tid + 256 * s;
            int r = f >> 3, kq = f & 7;
            float4 v = *(const float4*)&emb[(size_t)(r0 + r) * EN + k0 + kq * 4];
            us4 p;
            p[0] = f2b(v.x); p[1] = f2b(v.y); p[2] = f2b(v.z); p[3] = f2b(v.w);
            *(us4*)&A_lds[r][kq * 4] = p;
        }
        // stage B: 192x32 bf16 (rows of W16)
        #pragma unroll
        for (int s = 0; s < 3; ++s) {
            int f = tid + 256 * s;
            int row = f >> 2, ch = f & 3;
            *(us8*)&B_lds[row][ch * 8] = *(const us8*)&W16[(size_t)row * EN + k0 + ch * 8];
        }
        __syncthreads();

        short8 af[2], bf[6];
        #pragma unroll
        for (int rt = 0; rt < 2; ++rt)
            af[rt] = *(const short8*)&A_lds[32 * wm + 16 * rt + c][8 * g];
        #pragma unroll
        for (int nt = 0; nt < 6; ++nt)
            bf[nt] = *(const short8*)&B_lds[96 * wn + 16 * nt + c][8 * g];
        #pragma unroll
        for (int rt = 0; rt < 2; ++rt)
            #pragma unroll
            for (int nt = 0; nt < 6; ++nt)
                acc[rt][nt] = __builtin_amdgcn_mfma_f32_16x16x32_bf16(
                    af[rt], bf[nt], acc[rt][nt], 0, 0, 0);
        __syncthreads();
    }

    // epilogue: C/D layout col=lane&15, row=4*(lane>>4)+j  [m89 verified]
    #pragma unroll
    for (int rt = 0; rt < 2; ++rt) {
        #pragma unroll
        for (int nt = 0; nt < 6; ++nt) {
            const int n = 96 * wn + 16 * nt + c;
            const int wsel = n >> 6;
            const int d = n & 63;
            const int rbase = r0 + 32 * wm + 16 * rt + 4 * g;
            if (wsel < 2) {
                #pragma unroll
                for (int j = 0; j < 4; ++j)
                    QK[(size_t)wsel * BT * HN + (size_t)(rbase + j) * HN + d] =
                        f2b(acc[rt][nt][j]);
            } else {
                const int bb = rbase >> 12;       // batch
                const int tt = rbase & 4095;      // t within batch (4-row aligned)
                us4 p;
                #pragma unroll
                for (int j = 0; j < 4; ++j) p[j] = f2b(acc[rt][nt][j]);
                *(us4*)&VT[(size_t)bb * HN * TN + (size_t)d * TN + tt] = p;
            }
        }
    }
}

// ---------------------------------------------------------------------------
// Flash attention, bf16 MFMA, causal. QT=KT=64, 4 waves x 16 q-rows.
// Swapped QK: S^T = mfma(K, Q^T) -> lane holds S[k=4g+j][q=c]; softmax per
// q needs only 2 shfl_xor. P repacked via per-wave LDS into PV A-frags.
// V consumed from pre-transposed VT[b][d][t].
// ---------------------------------------------------------------------------
__global__ __launch_bounds__(256)
void attn(const unsigned short* __restrict__ QK,
          const unsigned short* __restrict__ VT, float* __restrict__ out) {
    __shared__ __align__(16) unsigned short Q_lds[64][72];     // [q][d]
    __shared__ __align__(16) unsigned short K_lds[64][72];     // [k][d]
    __shared__ __align__(16) unsigned short V_lds[64][72];     // [d][k]  (transposed V)
    __shared__ __align__(16) unsigned short P_lds[4][16][72];  // per wave [q][k]

    const int tid = threadIdx.x;
    const int w = tid >> 6, lane = tid & 63, c = lane & 15, g = lane >> 4;
    const int bid = blockIdx.x;
    const int b = bid & 3;
    const int qt = (TN / 64 - 1) - (bid >> 2);   // heavy q-tiles first

    const unsigned short* Qg = QK + ((size_t)b * TN + (size_t)qt * 64) * HN;
    const unsigned short* Kg = QK + (size_t)BT * HN + (size_t)b * TN * HN;
    const unsigned short* Vg = VT + (size_t)b * HN * TN;

    // stage Q tile once
    #pragma unroll
    for (int s = 0; s < 2; ++s) {
        int f = tid + 256 * s;
        int r = f >> 3, ch = f & 7;
        *(us8*)&Q_lds[r][ch * 8] = *(const us8*)&Qg[(size_t)r * HN + ch * 8];
    }
    __syncthreads();
    // Q fragments hoisted to registers (B-operand of swapped QK): q-col = c
    const short8 bq0 = *(const short8*)&Q_lds[16 * w + c][8 * g];
    const short8 bq1 = *(const short8*)&Q_lds[16 * w + c][32 + 8 * g];

    const f32x4 fzero = {0.f, 0.f, 0.f, 0.f};
    f32x4 o[4];
    #pragma unroll
    for (int nt = 0; nt < 4; ++nt) o[nt] = fzero;
    float m = -INFINITY, l = 0.f;

    for (int jt = 0; jt <= qt; ++jt) {
        // stage K (natural) and V (transposed rows) tiles
        #pragma unroll
        for (int s = 0; s < 2; ++s) {
            int f = tid + 256 * s;
            int r = f >> 3, ch = f & 7;
            *(us8*)&K_lds[r][ch * 8] =
                *(const us8*)&Kg[((size_t)jt * 64 + r) * HN + ch * 8];
            *(us8*)&V_lds[r][ch * 8] =
                *(const us8*)&Vg[(size_t)r * TN + (size_t)jt * 64 + ch * 8];
        }
        __syncthreads();

        const bool diag = (jt == qt);
        const int TMax = diag ? w : 3;   // wave-uniform; skip fully-masked tiles

        // S^T tiles: st[T] holds S[k=16T+4g+j][q=16w+c]
        f32x4 st[4];
        #pragma unroll
        for (int T = 0; T < 4; ++T) {
            if (T <= TMax) {
                short8 ak0 = *(const short8*)&K_lds[16 * T + c][8 * g];
                short8 ak1 = *(const short8*)&K_lds[16 * T + c][32 + 8 * g];
                f32x4 z = fzero;
                z = __builtin_amdgcn_mfma_f32_16x16x32_bf16(ak0, bq0, z, 0, 0, 0);
                st[T] = __builtin_amdgcn_mfma_f32_16x16x32_bf16(ak1, bq1, z, 0, 0, 0);
                if (diag && T == TMax) {
                    #pragma unroll
                    for (int j = 0; j < 4; ++j)
                        if (4 * g + j > c) st[T][j] = -INFINITY;  // causal
                }
            }
        }

        // online softmax (exp2 domain; log2e/32 folded into Wq)
        float pmax = -INFINITY;
        #pragma unroll
        for (int T = 0; T < 4; ++T)
            if (T <= TMax)
                #pragma unroll
                for (int j = 0; j < 4; ++j) pmax = fmaxf(pmax, st[T][j]);
        pmax = fmaxf(pmax, __shfl_xor(pmax, 16));
        pmax = fmaxf(pmax, __shfl_xor(pmax, 32));
        const float mn = fmaxf(m, pmax);
        const float alpha = fexp2(m - mn);
        float ls = 0.f;
        #pragma unroll
        for (int T = 0; T < 4; ++T)
            if (T <= TMax)
                #pragma unroll
                for (int j = 0; j < 4; ++j) {
                    float p = fexp2(st[T][j] - mn);   // masked -> exp2(-inf) = 0
                    st[T][j] = p;
                    ls += p;
                }
        ls += __shfl_xor(ls, 16);
        ls += __shfl_xor(ls, 32);
        l = l * alpha + ls;
        m = mn;

        // write P[q][k] bf16 to per-wave LDS (skipped tiles -> zeros)
        #pragma unroll
        for (int T = 0; T < 4; ++T) {
            if (T <= TMax) {
                us4 p;
                #pragma unroll
                for (int j = 0; j < 4; ++j) p[j] = f2b(st[T][j]);
                *(us4*)&P_lds[w][c][16 * T + 4 * g] = p;
            } else {
                us4 zp = {0, 0, 0, 0};
                *(us4*)&P_lds[w][c][16 * T + 4 * g] = zp;
            }
        }

        // rescale O by alpha of its rows (q = 4g+j): pull from lane 4g+j
        float a4[4];
        #pragma unroll
        for (int j = 0; j < 4; ++j) a4[j] = __shfl(alpha, 4 * g + j);
        #pragma unroll
        for (int nt = 0; nt < 4; ++nt)
            #pragma unroll
            for (int j = 0; j < 4; ++j) o[nt][j] *= a4[j];

        // PV: A = P (reform via LDS), B = V from transposed V_lds
        short8 pa0 = *(const short8*)&P_lds[w][c][8 * g];
        short8 pa1 = *(const short8*)&P_lds[w][c][32 + 8 * g];
        #pragma unroll
        for (int nt = 0; nt < 4; ++nt) {
            short8 bv0 = *(const short8*)&V_lds[c + 16 * nt][8 * g];
            short8 bv1 = *(const short8*)&V_lds[c + 16 * nt][32 + 8 * g];
            o[nt] = __builtin_amdgcn_mfma_f32_16x16x32_bf16(pa0, bv0, o[nt], 0, 0, 0);
            o[nt] = __builtin_amdgcn_mfma_f32_16x16x32_bf16(pa1, bv1, o[nt], 0, 0, 0);
        }
        __syncthreads();   // protect K/V LDS before next staging
    }

    // epilogue: O rows q = 4g+j, cols d = c+16nt; divide by row-sum l (at lane 4g+j)
    float linv[4];
    #pragma unroll
    for (int j = 0; j < 4; ++j) linv[j] = 1.f / __shfl(l, 4 * g + j);
    const size_t obase = ((size_t)b * TN + (size_t)qt * 64 + 16 * w + 4 * g) * HN;
    #pragma unroll
    for (int nt = 0; nt < 4; ++nt)
        #pragma unroll
        for (int j = 0; j < 4; ++j)
            out[obase + (size_t)j * HN + c + 16 * nt] = o[nt][j] * linv[j];
}

// ---------------------------------------------------------------------------
extern "C" void kernel_launch(void* const* d_in, const int* in_sizes, int n_in,
                              void* d_out, int out_size, void* d_ws, size_t ws_size,
                              hipStream_t stream) {
    const float* emb = (const float*)d_in[0];
    const float* Wq  = (const float*)d_in[1];
    const float* Wk  = (const float*)d_in[2];
    const float* Wv  = (const float*)d_in[3];
    float* out = (float*)d_out;

    unsigned short* ws  = (unsigned short*)d_ws;
    unsigned short* W16 = ws;                               // [192][1024]      384 KB
    unsigned short* QK  = ws + 196608;                      // [2][BT][64]      4 MB
    unsigned short* VT  = ws + 196608 + 2 * BT * HN;        // [4][64][4096]    2 MB

    wconv<<<192, 256, 0, stream>>>(Wq, Wk, Wv, W16);
    qkv_gemm<<<BT / 64, 256, 0, stream>>>(emb, W16, QK, VT);
    attn<<<BN * (TN / 64), 256, 0, stream>>>(QK, VT, out);
}

// Round 4
// 144.237 us; speedup vs baseline: 1.6472x; 1.6472x over previous
//
#include <hip/hip_runtime.h>
#include <math.h>
#include <stdint.h>

#define BN 4
#define TN 4096
#define EN 1024
#define HN 64
#define BT (BN*TN)

typedef __attribute__((ext_vector_type(8))) short   short8;   // 8 bf16 MFMA frag
typedef __attribute__((ext_vector_type(4))) float   f32x4;    // MFMA acc
typedef __attribute__((ext_vector_type(4))) unsigned short us4;
typedef __attribute__((ext_vector_type(8))) unsigned short us8;

// fp32 -> bf16 RNE
__device__ __forceinline__ unsigned short f2b(float f) {
    union { float f; uint32_t u; } v; v.f = f;
    uint32_t u = v.u;
    return (unsigned short)((u + 0x7FFFu + ((u >> 16) & 1u)) >> 16);
}

__device__ __forceinline__ float fexp2(float x) {
#if __has_builtin(__builtin_amdgcn_exp2f)
    return __builtin_amdgcn_exp2f(x);
#else
    return exp2f(x);
#endif
}

// ---------------------------------------------------------------------------
// W -> bf16. Rows 0-63: Wq scaled by log2(e)/32 (softmax in exp2 domain).
// Rows 64-127: Wk. Rows 128-191: Wv.
// ---------------------------------------------------------------------------
__global__ __launch_bounds__(256)
void wconv(const float* __restrict__ Wq, const float* __restrict__ Wk,
           const float* __restrict__ Wv, unsigned short* __restrict__ W16) {
    const int row = blockIdx.x;
    const int t = threadIdx.x;
    const float* src;
    float sc = 1.0f;
    if (row < 64)       { src = Wq + (size_t)row * EN; sc = 0.045084220f; }
    else if (row < 128) { src = Wk + (size_t)(row - 64) * EN; }
    else                { src = Wv + (size_t)(row - 128) * EN; }
    float4 v = *(const float4*)(src + t * 4);
    us4 p;
    p[0] = f2b(v.x * sc); p[1] = f2b(v.y * sc);
    p[2] = f2b(v.z * sc); p[3] = f2b(v.w * sc);
    *(us4*)&W16[(size_t)row * EN + t * 4] = p;
}

// ---------------------------------------------------------------------------
// QKV projection GEMM: C[16384][192] = emb * W16^T, bf16 MFMA.
// 512 threads = 8 waves (2M x 4N), block tile 64 x 192, K-step 64,
// double-buffered LDS, one barrier per K-step.
// Q,K written [wsel][r][d]; V written transposed [b][d][t].
// ---------------------------------------------------------------------------
__global__ __launch_bounds__(512, 2)
void qkv_gemm(const float* __restrict__ emb, const unsigned short* __restrict__ W16,
              unsigned short* __restrict__ QK, unsigned short* __restrict__ VT) {
    __shared__ __align__(16) unsigned short A_lds[2][64][72];
    __shared__ __align__(16) unsigned short B_lds[2][192][72];

    const int tid = threadIdx.x;
    const int wid = tid >> 6, lane = tid & 63;
    const int c = lane & 15, g = lane >> 4;
    const int wm = wid & 1, wn = wid >> 1;          // 2M x 4N waves
    const int r0 = blockIdx.x * 64;

    const int ar = tid >> 3, ach = tid & 7;         // A staging map

    const f32x4 fzero = {0.f, 0.f, 0.f, 0.f};
    f32x4 acc[2][3];
    #pragma unroll
    for (int i = 0; i < 2; ++i)
        #pragma unroll
        for (int j = 0; j < 3; ++j) acc[i][j] = fzero;

    // ---- prologue: stage K-step 0 into buf 0
    {
        float4 a0 = *(const float4*)&emb[(size_t)(r0 + ar) * EN + ach * 8];
        float4 a1 = *(const float4*)&emb[(size_t)(r0 + ar) * EN + ach * 8 + 4];
        us8 ap;
        ap[0] = f2b(a0.x); ap[1] = f2b(a0.y); ap[2] = f2b(a0.z); ap[3] = f2b(a0.w);
        ap[4] = f2b(a1.x); ap[5] = f2b(a1.y); ap[6] = f2b(a1.z); ap[7] = f2b(a1.w);
        *(us8*)&A_lds[0][ar][ach * 8] = ap;
        #pragma unroll
        for (int s = 0; s < 3; ++s) {
            const int f = tid + 512 * s;
            const int br = f >> 3, bch = f & 7;
            *(us8*)&B_lds[0][br][bch * 8] = *(const us8*)&W16[(size_t)br * EN + bch * 8];
        }
    }
    __syncthreads();

    for (int t = 0; t < 16; ++t) {
        const int cur = t & 1;
        const bool pf = (t < 15);
        const int kn = (t + 1) * 64;

        // issue next-tile global loads early (latency hides under MFMA)
        float4 a0, a1;
        us8 bw0, bw1, bw2;
        if (pf) {
            a0 = *(const float4*)&emb[(size_t)(r0 + ar) * EN + kn + ach * 8];
            a1 = *(const float4*)&emb[(size_t)(r0 + ar) * EN + kn + ach * 8 + 4];
            bw0 = *(const us8*)&W16[(size_t)((tid +    0) >> 3) * EN + kn + (tid & 7) * 8];
            bw1 = *(const us8*)&W16[(size_t)((tid +  512) >> 3) * EN + kn + ((tid + 512) & 7) * 8];
            bw2 = *(const us8*)&W16[(size_t)((tid + 1024) >> 3) * EN + kn + ((tid + 1024) & 7) * 8];
        }

        // compute current buffer
        short8 af[2][2], bf[3][2];
        #pragma unroll
        for (int rt = 0; rt < 2; ++rt)
            #pragma unroll
            for (int ks = 0; ks < 2; ++ks)
                af[rt][ks] = *(const short8*)&A_lds[cur][32 * wm + 16 * rt + c][32 * ks + 8 * g];
        #pragma unroll
        for (int nt = 0; nt < 3; ++nt)
            #pragma unroll
            for (int ks = 0; ks < 2; ++ks)
                bf[nt][ks] = *(const short8*)&B_lds[cur][48 * wn + 16 * nt + c][32 * ks + 8 * g];
        #pragma unroll
        for (int ks = 0; ks < 2; ++ks)
            #pragma unroll
            for (int rt = 0; rt < 2; ++rt)
                #pragma unroll
                for (int nt = 0; nt < 3; ++nt)
                    acc[rt][nt] = __builtin_amdgcn_mfma_f32_16x16x32_bf16(
                        af[rt][ks], bf[nt][ks], acc[rt][nt], 0, 0, 0);

        // write next tile into other buffer
        if (pf) {
            us8 ap;
            ap[0] = f2b(a0.x); ap[1] = f2b(a0.y); ap[2] = f2b(a0.z); ap[3] = f2b(a0.w);
            ap[4] = f2b(a1.x); ap[5] = f2b(a1.y); ap[6] = f2b(a1.z); ap[7] = f2b(a1.w);
            *(us8*)&A_lds[cur ^ 1][ar][ach * 8] = ap;
            *(us8*)&B_lds[cur ^ 1][(tid +    0) >> 3][((tid +    0) & 7) * 8] = bw0;
            *(us8*)&B_lds[cur ^ 1][(tid +  512) >> 3][((tid +  512) & 7) * 8] = bw1;
            *(us8*)&B_lds[cur ^ 1][(tid + 1024) >> 3][((tid + 1024) & 7) * 8] = bw2;
        }
        __syncthreads();
    }

    // epilogue: D row = 4g+j (A side), col = c (B side)  [validated layout]
    #pragma unroll
    for (int rt = 0; rt < 2; ++rt) {
        #pragma unroll
        for (int nt = 0; nt < 3; ++nt) {
            const int n = 48 * wn + 16 * nt + c;
            const int wsel = n >> 6;
            const int d = n & 63;
            const int rbase = r0 + 32 * wm + 16 * rt + 4 * g;
            if (wsel < 2) {
                #pragma unroll
                for (int j = 0; j < 4; ++j)
                    QK[(size_t)wsel * BT * HN + (size_t)(rbase + j) * HN + d] =
                        f2b(acc[rt][nt][j]);
            } else {
                const int bb = rbase >> 12;
                const int tt = rbase & 4095;
                us4 p;
                #pragma unroll
                for (int j = 0; j < 4; ++j) p[j] = f2b(acc[rt][nt][j]);
                *(us4*)&VT[(size_t)bb * HN * TN + (size_t)d * TN + tt] = p;
            }
        }
    }
}

// ---------------------------------------------------------------------------
// Flash attention, bf16 MFMA, causal. Q-tile 32, grid 512 (2 blocks/CU).
// 4 waves; wave w processes KV-tiles jt = w, w+4, ... INDEPENDENTLY (own LDS
// slot, no barriers in main loop), keeping private (m,l,O). Merge at end.
// ---------------------------------------------------------------------------
#define NW 4

__global__ __launch_bounds__(256, 2)
void attn(const unsigned short* __restrict__ QK,
          const unsigned short* __restrict__ VT, float* __restrict__ out) {
    __shared__ __align__(16) unsigned short KV[NW][2][64][72];  // per-wave K,V slots
    __shared__ __align__(16) float MLm[NW][32];
    __shared__ __align__(16) float MLl[NW][32];
    __shared__ __align__(16) float ML2m[32];
    __shared__ __align__(16) float ML2l[32];

    const int tid = threadIdx.x;
    const int w = tid >> 6, lane = tid & 63, c = lane & 15, g = lane >> 4;
    const int bid = blockIdx.x;
    const int b = bid & 3;
    const int qt = (TN / 32 - 1) - (bid >> 2);   // heavy q-tiles first

    const unsigned short* Qg = QK + ((size_t)b * TN + (size_t)qt * 32) * HN;
    const unsigned short* Kg = QK + (size_t)BT * HN + (size_t)b * TN * HN;
    const unsigned short* Vg = VT + (size_t)b * HN * TN;

    // Q fragments straight from global (L2/L3-resident)
    short8 bq[2][2];
    #pragma unroll
    for (int ct = 0; ct < 2; ++ct)
        #pragma unroll
        for (int ks = 0; ks < 2; ++ks)
            bq[ct][ks] = *(const short8*)&Qg[(size_t)(16 * ct + c) * HN + 32 * ks + 8 * g];

    const f32x4 fzero = {0.f, 0.f, 0.f, 0.f};
    f32x4 o[2][4];
    #pragma unroll
    for (int i = 0; i < 2; ++i)
        #pragma unroll
        for (int j = 0; j < 4; ++j) o[i][j] = fzero;
    float m[2] = {-INFINITY, -INFINITY};
    float l[2] = {0.f, 0.f};

    const int jmax = qt >> 1;
    unsigned short* Ks = &KV[w][0][0][0];
    unsigned short* Vs = &KV[w][1][0][0];

    for (int jt = w; jt <= jmax; jt += NW) {
        // ---- stage K, V into this wave's slot (wave-local, no barrier)
        #pragma unroll
        for (int i = 0; i < 8; ++i) {
            const int f = lane + 64 * i;
            const int r = f >> 3, ch = f & 7;
            *(us8*)&Ks[r * 72 + ch * 8] =
                *(const us8*)&Kg[((size_t)jt * 64 + r) * HN + ch * 8];
        }
        #pragma unroll
        for (int i = 0; i < 8; ++i) {
            const int f = lane + 64 * i;
            const int r = f >> 3, ch = f & 7;
            *(us8*)&Vs[r * 72 + ch * 8] =
                *(const us8*)&Vg[(size_t)r * TN + (size_t)jt * 64 + ch * 8];
        }

        // ---- S^T[64k][32q] = K . Q^T
        f32x4 st[4][2];
        #pragma unroll
        for (int kt = 0; kt < 4; ++kt)
            #pragma unroll
            for (int ct = 0; ct < 2; ++ct) st[kt][ct] = fzero;
        #pragma unroll
        for (int kt = 0; kt < 4; ++kt) {
            #pragma unroll
            for (int ks = 0; ks < 2; ++ks) {
                short8 ak = *(const short8*)&Ks[(16 * kt + c) * 72 + 32 * ks + 8 * g];
                #pragma unroll
                for (int ct = 0; ct < 2; ++ct)
                    st[kt][ct] = __builtin_amdgcn_mfma_f32_16x16x32_bf16(
                        ak, bq[ct][ks], st[kt][ct], 0, 0, 0);
            }
        }

        // ---- causal mask (only the last tile can cross the diagonal)
        if (jt == jmax) {
            const int koff = jt * 64 - qt * 32;    // k_in + koff vs q_in
            #pragma unroll
            for (int kt = 0; kt < 4; ++kt)
                #pragma unroll
                for (int ct = 0; ct < 2; ++ct)
                    #pragma unroll
                    for (int j = 0; j < 4; ++j)
                        if (16 * kt + 4 * g + j + koff > 16 * ct + c)
                            st[kt][ct][j] = -INFINITY;
        }

        // ---- online softmax (exp2 domain), per q = 16ct + c
        #pragma unroll
        for (int ct = 0; ct < 2; ++ct) {
            float pmax = -INFINITY;
            #pragma unroll
            for (int kt = 0; kt < 4; ++kt)
                #pragma unroll
                for (int j = 0; j < 4; ++j) pmax = fmaxf(pmax, st[kt][ct][j]);
            pmax = fmaxf(pmax, __shfl_xor(pmax, 16));
            pmax = fmaxf(pmax, __shfl_xor(pmax, 32));
            const float mn = fmaxf(m[ct], pmax);
            const float alpha = fexp2(m[ct] - mn);
            float ls = 0.f;
            #pragma unroll
            for (int kt = 0; kt < 4; ++kt)
                #pragma unroll
                for (int j = 0; j < 4; ++j) {
                    float p = fexp2(st[kt][ct][j] - mn);
                    st[kt][ct][j] = p;
                    ls += p;
                }
            ls += __shfl_xor(ls, 16);
            ls += __shfl_xor(ls, 32);
            l[ct] = l[ct] * alpha + ls;
            m[ct] = mn;

            // rescale O rows (q = 16qt' + 4g + j) by this alpha where qt' == ct
            float a4[4];
            #pragma unroll
            for (int j = 0; j < 4; ++j) a4[j] = __shfl(alpha, 4 * g + j);
            #pragma unroll
            for (int dt = 0; dt < 4; ++dt)
                #pragma unroll
                for (int j = 0; j < 4; ++j) o[ct][dt][j] *= a4[j];
        }

        // ---- write P[32q][64k] bf16 into the K slot (wave-local alias)
        #pragma unroll
        for (int kt = 0; kt < 4; ++kt)
            #pragma unroll
            for (int ct = 0; ct < 2; ++ct) {
                us4 p;
                #pragma unroll
                for (int j = 0; j < 4; ++j) p[j] = f2b(st[kt][ct][j]);
                *(us4*)&Ks[(16 * ct + c) * 72 + 16 * kt + 4 * g] = p;
            }

        // ---- O += P . V   (A = P rows, B = V^T rows from Vs)
        #pragma unroll
        for (int ks = 0; ks < 2; ++ks) {
            short8 pa[2];
            #pragma unroll
            for (int qp = 0; qp < 2; ++qp)
                pa[qp] = *(const short8*)&Ks[(16 * qp + c) * 72 + 32 * ks + 8 * g];
            #pragma unroll
            for (int dt = 0; dt < 4; ++dt) {
                short8 bv = *(const short8*)&Vs[(16 * dt + c) * 72 + 32 * ks + 8 * g];
                #pragma unroll
                for (int qp = 0; qp < 2; ++qp)
                    o[qp][dt] = __builtin_amdgcn_mfma_f32_16x16x32_bf16(
                        pa[qp], bv, o[qp][dt], 0, 0, 0);
            }
        }
    }

    // ---- publish per-wave m,l
    if (g == 0) {
        MLm[w][c]      = m[0];  MLl[w][c]      = l[0];
        MLm[w][c + 16] = m[1];  MLl[w][c + 16] = l[1];
    }
    __syncthreads();

    // ---- combine m,l across waves (first 32 threads)
    if (tid < 32) {
        const int q = tid;
        float M = MLm[0][q];
        #pragma unroll
        for (int s = 1; s < NW; ++s) M = fmaxf(M, MLm[s][q]);
        float L = 0.f;
        #pragma unroll
        for (int s = 0; s < NW; ++s) L += MLl[s][q] * fexp2(MLm[s][q] - M);
        ML2m[q] = M;
        ML2l[q] = L;
    }
    __syncthreads();

    // ---- scale own O and dump to per-wave f32 slot (reuse KV memory)
    float* Oslab = (float*)&KV[0][0][0][0];
    float* Ow = Oslab + w * (32 * 65);
    #pragma unroll
    for (int qp = 0; qp < 2; ++qp) {
        float mo[4];
        #pragma unroll
        for (int j = 0; j < 4; ++j) mo[j] = __shfl(m[qp], 4 * g + j);
        #pragma unroll
        for (int j = 0; j < 4; ++j) {
            const int q = 16 * qp + 4 * g + j;
            const float sc = fexp2(mo[j] - ML2m[q]);   // exp2(-inf)=0 for idle waves
            #pragma unroll
            for (int dt = 0; dt < 4; ++dt)
                Ow[q * 65 + 16 * dt + c] = o[qp][dt][j] * sc;
        }
    }
    __syncthreads();

    // ---- sum slots, normalize, write out. Wave w owns d-slice [16w,16w+16)
    const int d = 16 * w + c;
    #pragma unroll
    for (int tq = 0; tq < 8; ++tq) {
        const int q = 4 * tq + g;
        float v = 0.f;
        #pragma unroll
        for (int s = 0; s < NW; ++s) v += Oslab[s * (32 * 65) + q * 65 + d];
        out[((size_t)b * TN + (size_t)qt * 32 + q) * HN + d] = v / ML2l[q];
    }
}

// ---------------------------------------------------------------------------
extern "C" void kernel_launch(void* const* d_in, const int* in_sizes, int n_in,
                              void* d_out, int out_size, void* d_ws, size_t ws_size,
                              hipStream_t stream) {
    const float* emb = (const float*)d_in[0];
    const float* Wq  = (const float*)d_in[1];
    const float* Wk  = (const float*)d_in[2];
    const float* Wv  = (const float*)d_in[3];
    float* out = (float*)d_out;

    unsigned short* ws  = (unsigned short*)d_ws;
    unsigned short* W16 = ws;                               // [192][1024]   384 KB
    unsigned short* QK  = ws + 196608;                      // [2][BT][64]   4 MB
    unsigned short* VT  = ws + 196608 + 2 * (size_t)BT * HN; // [4][64][4096] 2 MB

    wconv<<<192, 256, 0, stream>>>(Wq, Wk, Wv, W16);
    qkv_gemm<<<BT / 64, 512, 0, stream>>>(emb, W16, QK, VT);
    attn<<<BN * (TN / 32), 256, 0, stream>>>(QK, VT, out);
}